// Round 9
// baseline (120.796 us; speedup 1.0000x reference)
//
#include <hip/hip_runtime.h>
#include <hip/hip_bf16.h>

typedef __attribute__((ext_vector_type(4))) float  f32x4;
typedef __attribute__((ext_vector_type(8))) short  bf16x8;

#define DIM       256
#define NBLOCKS   256
#define NTHREADS  512
#define TPB       8              // 128-token tiles per block
#define LDS_BYTES 131072         // W only: 256 rows x 512 B bf16, swizzled

#define WAITV(N) asm volatile("s_waitcnt vmcnt(" #N ")" ::: "memory")

__device__ __forceinline__ short f2bf(float x) {
    __hip_bfloat16 h = __float2bfloat16(x);
    return *reinterpret_cast<short*>(&h);
}

// Pinned-issue load: program order of asm volatiles == FIFO order; vmcnt
// retires IN ORDER, so WAITV(6) below is store-agnostic (see proof).
__device__ __forceinline__ f32x4 gload4(const float* p) {
    f32x4 r;
    asm volatile("global_load_dwordx4 %0, %1, off" : "=v"(r) : "v"(p) : "memory");
    return r;
}

// out[n][o] = sum_k X[n][k] * W0[o][k]  (router is degenerate: expert 0 always)
// 512 threads, min 2 waves/EU -> 256-VGPR cap: the register ring + acc[16]
// (~140 VGPR) fit WITHOUT spills. Rounds 6-8 failed at the 128-VGPR cap:
// scratch spills of in-flight asm-load destinations corrupt data.
__global__ __launch_bounds__(NTHREADS, 2)
void moe_expert0_kernel(const float* __restrict__ X,
                        const float* __restrict__ W0,
                        float* __restrict__ Out)
{
    extern __shared__ char lds[];
    const int tid  = threadIdx.x;
    const int lane = tid & 63;
    const int wave = tid >> 6;
    const int b    = blockIdx.x;

    // ---- stage full W (256x256) -> bf16, XOR-swizzled: row*512 + (cb ^ ((row&15)<<4))
    #pragma unroll
    for (int i = 0; i < 16; ++i) {
        int chunk = tid + i * NTHREADS;   // 8192 chunks of 8 floats
        int row = chunk >> 5;
        int c8  = chunk & 31;
        const f32x4* src = reinterpret_cast<const f32x4*>(W0 + row * DIM + c8 * 8);
        f32x4 f0 = src[0], f1 = src[1];
        bf16x8 w;
        w[0] = f2bf(f0[0]); w[1] = f2bf(f0[1]); w[2] = f2bf(f0[2]); w[3] = f2bf(f0[3]);
        w[4] = f2bf(f1[0]); w[5] = f2bf(f1[1]); w[6] = f2bf(f1[2]); w[7] = f2bf(f1[3]);
        int addr = row * 512 + ((c8 * 16) ^ ((row & 15) << 4));
        *reinterpret_cast<bf16x8*>(lds + addr) = w;
    }
    // Drain W loads (vmcnt -> 0 so asm FIFO counting starts clean) + ds_writes.
    asm volatile("s_waitcnt vmcnt(0) lgkmcnt(0)" ::: "memory");
    __builtin_amdgcn_s_barrier();
    // W is read-only from here: ZERO barriers in the main loop, waves free-run.

    const int l15 = lane & 15;
    const int lg  = lane >> 4;     // k-subgroup 0..3
    const int tg  = wave;          // 16-token group 0..7; this wave does ALL 256 chans

    // B-read (W): row = nt*16 + l15; swizzle term depends only on l15
    const int bbase = l15 * 512;
    const int bswz  = l15 << 4;

    // Per-lane A addressing: token row = b*1024 + t*128 + tg*16 + l15,
    // k-slice q (0..63): tile q>>3, k-floats (q&7)*32 + lg*8
    const float* xbase = X + (size_t)(b * 1024 + tg * 16 + l15) * DIM + lg * 8;
    float*       obase = Out + (size_t)(b * 1024 + tg * 16 + l15) * DIM + lg * 4;

    f32x4 Xa[4], Xb[4];            // 4-slot register ring (lookahead 3)
    #define GISSUE(SLOT, Q) do {                                               \
        int qg_ = (Q) > 63 ? 63 : (Q);                                         \
        const float* g_ = xbase + (size_t)(qg_ >> 3) * (128 * DIM)             \
                                + (qg_ & 7) * 32;                              \
        Xa[SLOT] = gload4(g_);                                                 \
        Xb[SLOT] = gload4(g_ + 4);                                             \
    } while (0)

    // prologue: pairs 0,1,2 in flight
    GISSUE(0, 0);
    GISSUE(1, 1);
    GISSUE(2, 2);

    for (int t = 0; t < TPB; ++t) {
        f32x4 acc[16];
        #pragma unroll
        for (int nt = 0; nt < 16; ++nt) acc[nt] = (f32x4)0.0f;

        #pragma unroll
        for (int s = 0; s < 8; ++s) {
            const int q = t * 8 + s;

            // 1. issue pair(q+3) into ring slot (s+3)&3
            GISSUE((s + 3) & 3, q + 3);

            // 2. wait for pair(q). vmcnt retires in order: if pair(q) were
            //    unretired, pairs q..q+3 (8 loads, plus any stores between)
            //    would all be outstanding -> vmcnt >= 8 > 6 keeps spinning.
            //    Hence vmcnt<=6 => pair(q) landed, independent of whether
            //    stores occupy vmcnt slots.
            WAITV(6);
            __builtin_amdgcn_sched_barrier(0);

            // 3. convert A fragment (k = s*32 + lg*8 + 0..7)
            f32x4 xa = Xa[s & 3], xb = Xb[s & 3];
            bf16x8 af;
            af[0] = f2bf(xa[0]); af[1] = f2bf(xa[1]);
            af[2] = f2bf(xa[2]); af[3] = f2bf(xa[3]);
            af[4] = f2bf(xb[0]); af[5] = f2bf(xb[1]);
            af[6] = f2bf(xb[2]); af[7] = f2bf(xb[3]);

            // 4. 16 MFMA: W-fragment as A-operand (swapped) so each lane's acc
            //    holds 4 consecutive output channels; covers all 256 chans
            #pragma unroll
            for (int nt = 0; nt < 16; ++nt) {
                bf16x8 bfr = *reinterpret_cast<const bf16x8*>(
                    lds + bbase + nt * 8192 + ((s * 64 + lg * 16) ^ bswz));
                acc[nt] = __builtin_amdgcn_mfma_f32_16x16x32_bf16(bfr, af, acc[nt], 0, 0, 0);
            }
        }

        // C stores (compiler stores; round-5-proven layout):
        // token = tg*16 + l15, chan = nt*16 + lg*4 + r  -> full 1 KB rows,
        // each store inst covers 16 rows x 64 B contiguous segments.
        {
            float* o = obase + (size_t)t * 128 * DIM;
            #pragma unroll
            for (int nt = 0; nt < 16; ++nt)
                *reinterpret_cast<f32x4*>(o + nt * 16) = acc[nt];
        }
    }
    WAITV(0);   // drain dangling tail prefetches before endpgm
    #undef GISSUE
}

extern "C" void kernel_launch(void* const* d_in, const int* in_sizes, int n_in,
                              void* d_out, int out_size, void* d_ws, size_t ws_size,
                              hipStream_t stream) {
    (void)in_sizes; (void)n_in; (void)d_ws; (void)ws_size; (void)out_size;
    const float* X = (const float*)d_in[0];
    const float* W = (const float*)d_in[1];   // [8,256,256]; expert 0 = first 65536
    float* Out = (float*)d_out;

    hipFuncSetAttribute((const void*)moe_expert0_kernel,
                        hipFuncAttributeMaxDynamicSharedMemorySize, LDS_BYTES);
    moe_expert0_kernel<<<dim3(NBLOCKS), dim3(NTHREADS), LDS_BYTES, stream>>>(X, W, Out);
}

// Round 10
// 114.524 us; speedup vs baseline: 1.0548x; 1.0548x over previous
//
#include <hip/hip_runtime.h>
#include <hip/hip_bf16.h>

typedef __attribute__((ext_vector_type(4))) float  f32x4;
typedef __attribute__((ext_vector_type(8))) short  bf16x8;
typedef __attribute__((ext_vector_type(4))) short  bf16x4;

#define DIM       256
#define NBLOCKS   256
#define NTHREADS  512
#define NROUNDS   16           // 64-token rounds per block (1024 tokens)
#define ABASE     131072       // A-buf: 64 rows x 512 B bf16, swizzled
#define LDS_BYTES 163840       // 128 KB W + 32 KB A = 160 KB exactly

#define WAITV(N) asm volatile("s_waitcnt vmcnt(" #N ")" ::: "memory")

__device__ __forceinline__ short f2bf(float x) {
    __hip_bfloat16 h = __float2bfloat16(x);
    return *reinterpret_cast<short*>(&h);
}

// Pinned-issue load; vmcnt retires in order, so counted waits below are exact.
__device__ __forceinline__ f32x4 gload4(const float* p) {
    f32x4 r;
    asm volatile("global_load_dwordx4 %0, %1, off" : "=v"(r) : "v"(p) : "memory");
    return r;
}

// out[n][o] = sum_k X[n][k] * W0[o][k]  (router is degenerate: expert 0 always)
__global__ __launch_bounds__(NTHREADS, 2)   // 256-VGPR cap: no spills (round-8 lesson)
void moe_expert0_kernel(const float* __restrict__ X,
                        const float* __restrict__ W0,
                        float* __restrict__ Out)
{
    extern __shared__ char lds[];
    const int tid  = threadIdx.x;
    const int lane = tid & 63;
    const int wave = tid >> 6;
    const int b    = blockIdx.x;

    // ---- stage full W (256x256) -> bf16, XOR-swizzled: row*512 + (cb ^ ((row&15)<<4))
    #pragma unroll
    for (int i = 0; i < 16; ++i) {
        int chunk = tid + i * NTHREADS;   // 8192 chunks of 8 floats
        int row = chunk >> 5;
        int c8  = chunk & 31;
        const f32x4* src = reinterpret_cast<const f32x4*>(W0 + row * DIM + c8 * 8);
        f32x4 f0 = src[0], f1 = src[1];
        bf16x8 w;
        w[0] = f2bf(f0[0]); w[1] = f2bf(f0[1]); w[2] = f2bf(f0[2]); w[3] = f2bf(f0[3]);
        w[4] = f2bf(f1[0]); w[5] = f2bf(f1[1]); w[6] = f2bf(f1[2]); w[7] = f2bf(f1[3]);
        int addr = row * 512 + ((c8 * 16) ^ ((row & 15) << 4));
        *reinterpret_cast<bf16x8*>(lds + addr) = w;
    }
    asm volatile("s_waitcnt vmcnt(0) lgkmcnt(0)" ::: "memory");  // clean vmcnt FIFO
    __builtin_amdgcn_s_barrier();

    const int l15 = lane & 15;
    const int lg  = lane >> 4;     // k-subgroup 0..3
    const int cg  = wave & 1;      // 128-chan half
    const int tg  = wave >> 1;     // 16-token group 0..3 within 64-token round

    // B-read (W): row = cg*128 + nt*16 + l15; row&15 == l15
    const int bbase = (cg * 128 + l15) * 512;
    const int bswz  = l15 << 4;

    // A-read (X buf): row = tg*16 + l15, frag bytes (s*64+lg*16) ^ ((row&15)<<4)
    const int abase_rd = ABASE + (tg * 16 + l15) * 512;
    const int aswz     = l15 << 4;                       // (row&15) == l15

    // A-stage: wave stages rows srow..srow+7; ONE gload4 per row = contiguous
    // 1 KB burst (lane i -> bytes [i*16, i*16+16) of the row) — copy-kernel
    // access pattern, line-adjacent for MSHR merging / DRAM locality.
    const int srow = wave * 8;

    const float* Xblk = X + (size_t)b * 1024 * DIM;
    float*       Oblk = Out + (size_t)b * 1024 * DIM;

    f32x4 Xrow[8];
    #define ALOAD(R) do {                                                      \
        _Pragma("unroll")                                                      \
        for (int jj = 0; jj < 8; ++jj)                                         \
            Xrow[jj] = gload4(Xblk + (size_t)((R) * 64 + srow + jj) * DIM      \
                              + lane * 4);                                     \
    } while (0)
    // cvt + swizzled ds_write: pre-swz slot = lane>>1, dest slot ^= row&15
    #define ASTORE() do {                                                      \
        _Pragma("unroll")                                                      \
        for (int jj = 0; jj < 8; ++jj) {                                       \
            int row_ = srow + jj;                                              \
            f32x4 xv = Xrow[jj];                                               \
            bf16x4 xw;                                                         \
            xw[0] = f2bf(xv[0]); xw[1] = f2bf(xv[1]);                          \
            xw[2] = f2bf(xv[2]); xw[3] = f2bf(xv[3]);                          \
            int dst = ABASE + row_ * 512                                       \
                    + ((((lane >> 1) ^ (row_ & 15)) << 4)) + (lane & 1) * 8;   \
            *reinterpret_cast<bf16x4*>(lds + dst) = xw;                        \
        }                                                                      \
    } while (0)

    // prologue: round 0 staged, round 1 loads in flight
    ALOAD(0);
    WAITV(0); __builtin_amdgcn_sched_barrier(0);
    ASTORE();
    ALOAD(1);
    asm volatile("s_waitcnt lgkmcnt(0)" ::: "memory");
    __builtin_amdgcn_s_barrier();

    for (int r = 0; r < NROUNDS; ++r) {
        f32x4 acc[8];
        #pragma unroll
        for (int nt = 0; nt < 8; ++nt) acc[nt] = (f32x4)0.0f;

        #pragma unroll
        for (int s = 0; s < 8; ++s) {
            bf16x8 af = *reinterpret_cast<const bf16x8*>(
                lds + abase_rd + ((s * 64 + lg * 16) ^ aswz));
            #pragma unroll
            for (int nt = 0; nt < 8; ++nt) {
                bf16x8 bfr = *reinterpret_cast<const bf16x8*>(
                    lds + bbase + nt * 8192 + ((s * 64 + lg * 16) ^ bswz));
                acc[nt] = __builtin_amdgcn_mfma_f32_16x16x32_bf16(bfr, af, acc[nt], 0, 0, 0);
            }
        }

        // C stores (compiler stores; round-9-proven layout, cg offset added):
        // token = tg*16+l15, chan = cg*128 + nt*16 + lg*4 + reg
        {
            float* o = Oblk + (size_t)(r * 64 + tg * 16 + l15) * DIM
                     + cg * 128 + lg * 4;
            #pragma unroll
            for (int nt = 0; nt < 8; ++nt)
                *reinterpret_cast<f32x4*>(o + nt * 16) = acc[nt];
        }

        __builtin_amdgcn_s_barrier();        // all waves done reading A(r)
        if (r + 1 < NROUNDS) {
            // loads(r+1) are OLDER than this round's 8 stores: vmcnt<=8 =>
            // loads(r+1) landed (in-order retirement), store-agnostic.
            WAITV(8); __builtin_amdgcn_sched_barrier(0);
            ASTORE();                         // write A(r+1)
            if (r + 2 < NROUNDS) ALOAD(r + 2);
            asm volatile("s_waitcnt lgkmcnt(0)" ::: "memory");
        }
        __builtin_amdgcn_s_barrier();        // A(r+1) visible
    }
    WAITV(0);   // drain tail stores before endpgm
    #undef ALOAD
    #undef ASTORE
}

extern "C" void kernel_launch(void* const* d_in, const int* in_sizes, int n_in,
                              void* d_out, int out_size, void* d_ws, size_t ws_size,
                              hipStream_t stream) {
    (void)in_sizes; (void)n_in; (void)d_ws; (void)ws_size; (void)out_size;
    const float* X = (const float*)d_in[0];
    const float* W = (const float*)d_in[1];   // [8,256,256]; expert 0 = first 65536
    float* Out = (float*)d_out;

    hipFuncSetAttribute((const void*)moe_expert0_kernel,
                        hipFuncAttributeMaxDynamicSharedMemorySize, LDS_BYTES);
    moe_expert0_kernel<<<dim3(NBLOCKS), dim3(NTHREADS), LDS_BYTES, stream>>>(X, W, Out);
}